// Round 15
// baseline (237.248 us; speedup 1.0000x reference)
//
#include <hip/hip_runtime.h>
#include <hip/hip_bf16.h>

// LGM loss: logits/margin_logits [8192,10000] f32 + scalar likelihood.
// R15: WRITE RUN-LENGTH test. Ledger sorted by write-stream shape:
//   fill (monotone >=1KB/instr) 6.7 TB/s | R6/R14 (512B/row segments) 3.6-4
//   | R8 (isolated 512B) 2.5. All instruction-level and occupancy levers
// exhausted; run length per row per tile visit has never been raised.
// BM=64 x BN=256 -> 1024B/row/visit, XCD's co-resident blocks paint
// contiguous-KB spans. Everything else = R6 skeleton: reg-staged dbuf LDS
// (A 2x8KB + B 2x32KB = 80KB, 2 blocks/CU), XOR swizzle, BK=64, 512 thr,
// 8 waves 1Mx8N (wave = 64x32, same frag code), nt-fastest bijective map,
// lik fold. Single variable vs R6.

#define ALPHA_ 0.1f
constexpr int BATCH = 8192;
constexpr int NCLS  = 10000;
constexpr int FDIM  = 256;

typedef __attribute__((ext_vector_type(8))) short bf16x8;
typedef __attribute__((ext_vector_type(4))) float f32x4;

__device__ __forceinline__ unsigned short f2bf(float f) {
  unsigned int u = __float_as_uint(f);
  u += 0x7FFF + ((u >> 16) & 1);   // round-to-nearest-even
  return (unsigned short)(u >> 16);
}

// One wave per row: convert f32 row -> bf16 into ws, and compute sum(x*x).
__global__ void prep_kernel(const float* __restrict__ feat,
                            const float* __restrict__ centers,
                            unsigned short* __restrict__ fbf,
                            unsigned short* __restrict__ cbf,
                            float* __restrict__ fsq,
                            float* __restrict__ csq) {
  int gw = (int)((blockIdx.x * blockDim.x + threadIdx.x) >> 6);
  int lane = threadIdx.x & 63;
  if (gw >= BATCH + NCLS) return;
  const float* src; unsigned short* dst; float* sq;
  if (gw < BATCH) {
    src = feat + (size_t)gw * FDIM; dst = fbf + (size_t)gw * FDIM; sq = fsq + gw;
  } else {
    int r = gw - BATCH;
    src = centers + (size_t)r * FDIM; dst = cbf + (size_t)r * FDIM; sq = csq + r;
  }
  float4 v = reinterpret_cast<const float4*>(src)[lane];   // 64 lanes x 16B = 256 f32
  ushort4 b;
  b.x = f2bf(v.x); b.y = f2bf(v.y); b.z = f2bf(v.z); b.w = f2bf(v.w);
  reinterpret_cast<ushort4*>(dst)[lane] = b;
  float s = v.x*v.x + v.y*v.y + v.z*v.z + v.w*v.w;
  #pragma unroll
  for (int off = 32; off >= 1; off >>= 1) s += __shfl_xor(s, off, 64);
  if (lane == 0) *sq = s;
}

// 64x256 tile, BK=64, 8 waves (1Mx8N), each wave 64x32 via 4x2 frags of 16x16x32.
#define BM 64
#define BN 256
#define BK 64
constexpr int NTN = 40;                  // ceil(10000/256); tail tile 16 valid cols
constexpr int NWG = (BATCH / BM) * NTN;  // 128*40 = 5120 == 8*640

__global__ __launch_bounds__(512, 4)
void gemm_kernel(const unsigned short* __restrict__ fbf,
                 const unsigned short* __restrict__ cbf,
                 const float* __restrict__ fsq,
                 const float* __restrict__ csq,
                 const int* __restrict__ label,
                 float* __restrict__ out_logits,
                 float* __restrict__ out_margin,
                 float* __restrict__ lik_row) {
  // Double-buffered, XOR-swizzled (slot = chunk ^ (row&7), 16B chunks).
  __shared__ unsigned short As[2][BM * BK];   // 8 KB each
  __shared__ unsigned short Bs[2][BN * BK];   // 32 KB each -> 80 KB total

  // XCD-bijective split, nt-fastest within each XCD chunk: ~16 co-resident
  // blocks per XCD paint consecutive 1KB row-segments of one 64-row band.
  int bid = blockIdx.x;
  int wg = (bid & 7) * (NWG >> 3) + (bid >> 3);
  int mt = wg / NTN;
  int nt = wg - mt * NTN;
  const int c0 = nt * BN;

  const int tid  = threadIdx.x;
  const int lane = tid & 63;
  const int wid  = tid >> 6;            // 0..7
  const int wc   = wid * 32;            // 8 waves across N; all waves span M=64
  const int sr   = tid >> 3;            // staging row 0..63
  const int sc   = tid & 7;             // staging 16B chunk 0..7
  const int mloc  = lane & 15;
  const int nbase = wc + ((lane >> 4) << 2);

  const size_t a_base = (size_t)(mt * BM) * FDIM;

  f32x4 acc[4][2];
  #pragma unroll
  for (int i = 0; i < 4; i++)
    #pragma unroll
    for (int j = 0; j < 2; j++) acc[i][j] = (f32x4){0.f, 0.f, 0.f, 0.f};

  bf16x8 va, vb[4];
  #define LOADT(k0_) do {                                                      \
    va = *reinterpret_cast<const bf16x8*>(fbf + a_base + (size_t)sr * FDIM + (k0_) + sc * 8); \
    _Pragma("unroll")                                                          \
    for (int j = 0; j < 4; ++j) {                                              \
      int cc = c0 + j * 64 + sr; cc = (cc < NCLS) ? cc : (NCLS - 1);           \
      vb[j] = *reinterpret_cast<const bf16x8*>(cbf + (size_t)cc * FDIM + (k0_) + sc * 8); \
    }                                                                          \
  } while (0)

  #define STORET(b_) do {                                                      \
    int offa = sr * BK + ((sc ^ (sr & 7)) * 8);                                \
    *reinterpret_cast<bf16x8*>(&As[b_][offa]) = va;                            \
    _Pragma("unroll")                                                          \
    for (int j = 0; j < 4; ++j) {                                              \
      int r = j * 64 + sr;                                                     \
      int off = r * BK + ((sc ^ (r & 7)) * 8);                                 \
      *reinterpret_cast<bf16x8*>(&Bs[b_][off]) = vb[j];                        \
    }                                                                          \
  } while (0)

  LOADT(0);
  STORET(0);

  #pragma unroll
  for (int kc = 0; kc < FDIM / BK; ++kc) {
    const int cur = kc & 1;
    if (kc < FDIM / BK - 1) LOADT((kc + 1) * BK);
    __syncthreads();                          // buf[cur] writes visible
    #pragma unroll
    for (int kk = 0; kk < BK / 32; ++kk) {
      const int ch = kk * 4 + (lane >> 4);    // 16B chunk within row
      bf16x8 a[4], b[2];
      #pragma unroll
      for (int i = 0; i < 4; i++) {
        int row = i * 16 + (lane & 15);
        a[i] = *reinterpret_cast<const bf16x8*>(&As[cur][row * BK + ((ch ^ (row & 7)) * 8)]);
      }
      #pragma unroll
      for (int j = 0; j < 2; j++) {
        int row = wc + j * 16 + (lane & 15);
        b[j] = *reinterpret_cast<const bf16x8*>(&Bs[cur][row * BK + ((ch ^ (row & 7)) * 8)]);
      }
      // Swapped operands: per lane, reg r = 4 consecutive N columns at one M row.
      #pragma unroll
      for (int i = 0; i < 4; i++)
        #pragma unroll
        for (int j = 0; j < 2; j++)
          acc[i][j] = __builtin_amdgcn_mfma_f32_16x16x32_bf16(b[j], a[i], acc[i][j], 0, 0, 0);
    }
    if (kc < FDIM / BK - 1) STORET(cur ^ 1);  // fill other buffer
  }

  // Epilogue: logits = acc - 0.5*(fsq+csq); margin; lik fold.
  #pragma unroll
  for (int i = 0; i < 4; i++) {
    int m = mt * BM + mloc + i * 16;
    float fs = fsq[m];
    int lb = label[m];
    size_t rowoff = (size_t)m * NCLS;
    #pragma unroll
    for (int j = 0; j < 2; j++) {
      int n0 = c0 + nbase + j * 16;
      if (n0 >= NCLS) continue;   // NCLS%4==0 and n0%4==0 -> float4 all-or-nothing
      float4 cs = *reinterpret_cast<const float4*>(&csq[n0]);
      f32x4 v = acc[i][j];
      f32x4 lg;
      lg[0] = v[0] - 0.5f * (fs + cs.x);
      lg[1] = v[1] - 0.5f * (fs + cs.y);
      lg[2] = v[2] - 0.5f * (fs + cs.z);
      lg[3] = v[3] - 0.5f * (fs + cs.w);
      *reinterpret_cast<f32x4*>(&out_logits[rowoff + n0]) = lg;
      f32x4 mg;
      mg[0] = (lb == n0    ) ? lg[0] * (1.0f + ALPHA_) : lg[0];
      mg[1] = (lb == n0 + 1) ? lg[1] * (1.0f + ALPHA_) : lg[1];
      mg[2] = (lb == n0 + 2) ? lg[2] * (1.0f + ALPHA_) : lg[2];
      mg[3] = (lb == n0 + 3) ? lg[3] * (1.0f + ALPHA_) : lg[3];
      *reinterpret_cast<f32x4*>(&out_margin[rowoff + n0]) = mg;
      if (lb >= n0 && lb < n0 + 4) {
        float lv = (lb == n0) ? lg[0] : (lb == n0 + 1) ? lg[1]
                 : (lb == n0 + 2) ? lg[2] : lg[3];
        lik_row[m] = -lv;   // exactly one thread in grid writes each m
      }
    }
  }
  #undef LOADT
  #undef STORET
}

// likelihood = (1/B) * sum_m lik_row[m]; 1024 threads, deterministic tree.
__global__ void lik_reduce_kernel(const float* __restrict__ lik_row,
                                  float* __restrict__ out) {
  int t = threadIdx.x;  // 1024
  float v = 0.f;
  #pragma unroll
  for (int i = 0; i < BATCH / 1024; i++) v += lik_row[t + i * 1024];
  #pragma unroll
  for (int off = 32; off >= 1; off >>= 1) v += __shfl_xor(v, off, 64);
  __shared__ float red[16];
  if ((t & 63) == 0) red[t >> 6] = v;
  __syncthreads();
  if (t == 0) {
    float s = 0.f;
    #pragma unroll
    for (int i = 0; i < 16; i++) s += red[i];
    out[0] = s * (1.0f / BATCH);
  }
}

extern "C" void kernel_launch(void* const* d_in, const int* in_sizes, int n_in,
                              void* d_out, int out_size, void* d_ws, size_t ws_size,
                              hipStream_t stream) {
  const float* feat    = (const float*)d_in[0];
  const int*   label   = (const int*)d_in[1];
  const float* centers = (const float*)d_in[2];

  float* out        = (float*)d_out;
  float* out_logits = out;
  float* out_margin = out + (size_t)BATCH * NCLS;
  float* out_lik    = out + 2 * (size_t)BATCH * NCLS;

  char* ws = (char*)d_ws;
  unsigned short* fbf = (unsigned short*)ws;                                   // 4 MB
  unsigned short* cbf = (unsigned short*)(ws + (size_t)BATCH * FDIM * 2);      // 5 MB
  float* fsq     = (float*)(ws + (size_t)BATCH * FDIM * 2 + (size_t)NCLS * FDIM * 2);
  float* csq     = fsq + BATCH;
  float* lik_row = csq + NCLS;

  prep_kernel<<<(BATCH + NCLS) / 4, 256, 0, stream>>>(feat, centers, fbf, cbf, fsq, csq);
  gemm_kernel<<<NWG, 512, 0, stream>>>(
      fbf, cbf, fsq, csq, label, out_logits, out_margin, lik_row);
  lik_reduce_kernel<<<1, 1024, 0, stream>>>(lik_row, out_lik);
}

// Round 16
// 234.475 us; speedup vs baseline: 1.0118x; 1.0118x over previous
//
#include <hip/hip_runtime.h>
#include <hip/hip_bf16.h>

// LGM loss: logits/margin_logits [8192,10000] f32 + scalar likelihood.
// R16: TRANSACTION-RATE attack (R3 retried unconfounded). Insight: FETCH_SIZE
// counts HBM only -> R11's 198MB fetch was output-RFO (R14 killed it, -3us
// only) => not bytes-bound. Remaining delta vs fill kernel: transactions/byte.
// Our fragment stores = 16 rows x 64B per instr (1 txn/64B); fill = 1KB
// contiguous (1 txn/128B). R3 tested full-line runs but at 2 waves/SIMD
// (pre-occupancy fix, latency-masked -> confounded null). Now: R14 base
// (halo frags, dbuf reg-staged LDS, 4 waves/SIMD) + epilogue staged through
// union'd LDS; readback stores 2 rows x 512B contiguous per instruction with
// parity-aligned run starts (even rows at c0, odd at c0-16; both == 0 mod
// 128 -> zero partial lines, minimal transactions). Margin+lik at readback.

#define ALPHA_ 0.1f
constexpr int BATCH = 8192;
constexpr int NCLS  = 10000;
constexpr int FDIM  = 256;

typedef __attribute__((ext_vector_type(8))) short bf16x8;
typedef __attribute__((ext_vector_type(4))) float f32x4;

__device__ __forceinline__ unsigned short f2bf(float f) {
  unsigned int u = __float_as_uint(f);
  u += 0x7FFF + ((u >> 16) & 1);   // round-to-nearest-even
  return (unsigned short)(u >> 16);
}

// One wave per row: convert f32 row -> bf16 into ws, and compute sum(x*x).
__global__ void prep_kernel(const float* __restrict__ feat,
                            const float* __restrict__ centers,
                            unsigned short* __restrict__ fbf,
                            unsigned short* __restrict__ cbf,
                            float* __restrict__ fsq,
                            float* __restrict__ csq) {
  int gw = (int)((blockIdx.x * blockDim.x + threadIdx.x) >> 6);
  int lane = threadIdx.x & 63;
  if (gw >= BATCH + NCLS) return;
  const float* src; unsigned short* dst; float* sq;
  if (gw < BATCH) {
    src = feat + (size_t)gw * FDIM; dst = fbf + (size_t)gw * FDIM; sq = fsq + gw;
  } else {
    int r = gw - BATCH;
    src = centers + (size_t)r * FDIM; dst = cbf + (size_t)r * FDIM; sq = csq + r;
  }
  float4 v = reinterpret_cast<const float4*>(src)[lane];   // 64 lanes x 16B = 256 f32
  ushort4 b;
  b.x = f2bf(v.x); b.y = f2bf(v.y); b.z = f2bf(v.z); b.w = f2bf(v.w);
  reinterpret_cast<ushort4*>(dst)[lane] = b;
  float s = v.x*v.x + v.y*v.y + v.z*v.z + v.w*v.w;
  #pragma unroll
  for (int off = 32; off >= 1; off >>= 1) s += __shfl_xor(s, off, 64);
  if (lane == 0) *sq = s;
}

// 128x128 tile (+16-col B halo), BK=64, 8 waves (2Mx4N), wave = 64x32 (+16 halo).
#define BM 128
#define BN 128
#define BK 64
#define BROWS 144   // 16-row halo + 128
#define CTS 148     // ct row stride (f32): 144 cols + 4 pad

__global__ __launch_bounds__(512, 4)
void gemm_kernel(const unsigned short* __restrict__ fbf,
                 const unsigned short* __restrict__ cbf,
                 const float* __restrict__ fsq,
                 const float* __restrict__ csq,
                 const int* __restrict__ label,
                 float* __restrict__ out_logits,
                 float* __restrict__ out_margin,
                 float* __restrict__ lik_row) {
  // K-loop staging and epilogue C-staging share LDS (As/Bs dead after K-loop).
  __shared__ union SMem {
    struct { unsigned short A[2][BM * BK]; unsigned short B[2][BROWS * BK]; } ab; // 68 KB
    float ct[64 * CTS];                                                           // 37 KB
  } sm;

  const int NTN = (NCLS + BN - 1) / BN;  // 79
  const int NWG = (BATCH / BM) * NTN;    // 5056 == 8 * 632

  // XCD-bijective split, nt-fastest within each XCD chunk.
  int bid = blockIdx.x;
  int wg = (bid & 7) * (NWG >> 3) + (bid >> 3);
  int mt = wg / NTN;
  int nt = wg - mt * NTN;

  const int tid  = threadIdx.x;
  const int lane = tid & 63;
  const int wid  = tid >> 6;            // 0..7
  const int wr   = (wid >> 2) * 64;     // 2 waves in M
  const int wc   = (wid & 3) * 32;      // 4 waves in N
  const int sr   = tid >> 3;            // staging row 0..63
  const int sc   = tid & 7;             // staging 16B chunk 0..7

  const size_t a_base = (size_t)(mt * BM) * FDIM;
  const int c0 = nt * BN;

  f32x4 acc[4][3];   // 3 N-frags: j=0 is the 16-col halo at wc-16
  #pragma unroll
  for (int i = 0; i < 4; i++)
    #pragma unroll
    for (int j = 0; j < 3; j++) acc[i][j] = (f32x4){0.f, 0.f, 0.f, 0.f};

  bf16x8 va[2], vb[2], vbh;

  // Bs row r <-> class c0 - 16 + r, r in [0,144).
  #define LOADT(k0_) do {                                                      \
    _Pragma("unroll")                                                          \
    for (int j = 0; j < 2; ++j) {                                              \
      int r = j * 64 + sr;                                                     \
      va[j] = *reinterpret_cast<const bf16x8*>(fbf + a_base + (size_t)r * FDIM + (k0_) + sc * 8); \
      int cc = c0 + r; cc = (cc < NCLS) ? cc : (NCLS - 1);                     \
      vb[j] = *reinterpret_cast<const bf16x8*>(cbf + (size_t)cc * FDIM + (k0_) + sc * 8); \
    }                                                                          \
    if (tid < 128) {                                                           \
      int ch_ = c0 - 16 + (tid >> 3); ch_ = (ch_ >= 0) ? ch_ : 0;              \
      vbh = *reinterpret_cast<const bf16x8*>(cbf + (size_t)ch_ * FDIM + (k0_) + sc * 8); \
    }                                                                          \
  } while (0)

  #define STORET(b_) do {                                                      \
    _Pragma("unroll")                                                          \
    for (int j = 0; j < 2; ++j) {                                              \
      int r = j * 64 + sr;                                                     \
      int offa = r * BK + ((sc ^ (r & 7)) * 8);                                \
      *reinterpret_cast<bf16x8*>(&sm.ab.A[b_][offa]) = va[j];                  \
      int rb = r + 16;                                                         \
      int offb = rb * BK + ((sc ^ (rb & 7)) * 8);                              \
      *reinterpret_cast<bf16x8*>(&sm.ab.B[b_][offb]) = vb[j];                  \
    }                                                                          \
    if (tid < 128) {                                                           \
      int rh = tid >> 3;                                                       \
      int offh = rh * BK + ((sc ^ (rh & 7)) * 8);                              \
      *reinterpret_cast<bf16x8*>(&sm.ab.B[b_][offh]) = vbh;                    \
    }                                                                          \
  } while (0)

  LOADT(0);
  STORET(0);

  #pragma unroll
  for (int kc = 0; kc < FDIM / BK; ++kc) {
    const int cur = kc & 1;
    if (kc < FDIM / BK - 1) LOADT((kc + 1) * BK);
    __syncthreads();                          // buf[cur] writes visible
    #pragma unroll
    for (int kk = 0; kk < BK / 32; ++kk) {
      const int ch = kk * 4 + (lane >> 4);    // 16B chunk within row
      bf16x8 a[4], b[3];
      #pragma unroll
      for (int i = 0; i < 4; i++) {
        int row = wr + i * 16 + (lane & 15);
        a[i] = *reinterpret_cast<const bf16x8*>(&sm.ab.A[cur][row * BK + ((ch ^ (row & 7)) * 8)]);
      }
      #pragma unroll
      for (int j = 0; j < 3; j++) {
        int row = wc + j * 16 + (lane & 15);  // class c0 - 16 + wc + j*16 + (lane&15)
        b[j] = *reinterpret_cast<const bf16x8*>(&sm.ab.B[cur][row * BK + ((ch ^ (row & 7)) * 8)]);
      }
      #pragma unroll
      for (int i = 0; i < 4; i++)
        #pragma unroll
        for (int j = 0; j < 3; j++)
          acc[i][j] = __builtin_amdgcn_mfma_f32_16x16x32_bf16(b[j], a[i], acc[i][j], 0, 0, 0);
    }
    if (kc < FDIM / BK - 1) STORET(cur ^ 1);  // fill other buffer
  }
  __syncthreads();   // As/Bs reads complete before union reuse as ct

  // ---- Epilogue: stage logits window [c0-16, c0+128) per 64-row chunk into
  // LDS, then readback as 512B-contiguous parity-aligned runs per row. ----
  #pragma unroll
  for (int chk = 0; chk < 2; ++chk) {
    if ((wid >> 2) == chk) {   // waves owning rows [chk*64, chk*64+64)
      #pragma unroll
      for (int i = 0; i < 4; i++) {
        int rr = i * 16 + (lane & 15);              // row within chunk
        int m  = mt * BM + chk * 64 + rr;
        float fs = fsq[m];
        #pragma unroll
        for (int j = 0; j < 3; j++) {
          int wcol = wc + (j - 1) * 16 + ((lane >> 4) << 2) + 16;  // 0..143
          int col  = c0 - 16 + wcol;
          int ccl  = (col < 0) ? 0 : ((col > NCLS - 4) ? (NCLS - 4) : col);
          float4 cs = *reinterpret_cast<const float4*>(&csq[ccl]);
          f32x4 v = acc[i][j];
          f32x4 lg;
          lg[0] = v[0] - 0.5f * (fs + cs.x);
          lg[1] = v[1] - 0.5f * (fs + cs.y);
          lg[2] = v[2] - 0.5f * (fs + cs.z);
          lg[3] = v[3] - 0.5f * (fs + cs.w);
          // overlapping window writes between waves carry identical values
          *reinterpret_cast<f32x4*>(&sm.ct[rr * CTS + wcol]) = lg;
        }
      }
    }
    __syncthreads();
    // Readback: per instruction a wave covers 2 rows x 512B contiguous.
    // Even rows: cols [c0, c0+128); odd rows: [c0-16, c0+112). Both runs
    // start 0 mod 128 (row stride 40000 == 64 mod 128; 64+64=0). Exact
    // partition of [0,NCLS) per parity across nt.
    #pragma unroll
    for (int it = 0; it < 4; ++it) {
      int rr = it * 16 + (tid >> 5);                // row within chunk
      int p  = rr & 1;
      int cidx = (tid & 31) << 2;                   // 0..124
      int widx = (p ? 0 : 16) + cidx;
      int n0 = c0 - (p ? 16 : 0) + cidx;
      if (n0 < 0 || n0 >= NCLS) continue;           // n0%4==0 -> all-or-nothing
      int m  = mt * BM + chk * 64 + rr;
      f32x4 lg = *reinterpret_cast<const f32x4*>(&sm.ct[rr * CTS + widx]);
      size_t idx = (size_t)m * NCLS + n0;
      *reinterpret_cast<f32x4*>(&out_logits[idx]) = lg;
      int lb = label[m];
      f32x4 mg;
      mg[0] = (lb == n0    ) ? lg[0] * (1.0f + ALPHA_) : lg[0];
      mg[1] = (lb == n0 + 1) ? lg[1] * (1.0f + ALPHA_) : lg[1];
      mg[2] = (lb == n0 + 2) ? lg[2] * (1.0f + ALPHA_) : lg[2];
      mg[3] = (lb == n0 + 3) ? lg[3] * (1.0f + ALPHA_) : lg[3];
      *reinterpret_cast<f32x4*>(&out_margin[idx]) = mg;
      if (lb >= n0 && lb < n0 + 4) {
        float lv = (lb == n0) ? lg[0] : (lb == n0 + 1) ? lg[1]
                 : (lb == n0 + 2) ? lg[2] : lg[3];
        lik_row[m] = -lv;   // parity windows partition cols -> single writer
      }
    }
    __syncthreads();
  }
  #undef LOADT
  #undef STORET
}

// likelihood = (1/B) * sum_m lik_row[m]; 1024 threads, deterministic tree.
__global__ void lik_reduce_kernel(const float* __restrict__ lik_row,
                                  float* __restrict__ out) {
  int t = threadIdx.x;  // 1024
  float v = 0.f;
  #pragma unroll
  for (int i = 0; i < BATCH / 1024; i++) v += lik_row[t + i * 1024];
  #pragma unroll
  for (int off = 32; off >= 1; off >>= 1) v += __shfl_xor(v, off, 64);
  __shared__ float red[16];
  if ((t & 63) == 0) red[t >> 6] = v;
  __syncthreads();
  if (t == 0) {
    float s = 0.f;
    #pragma unroll
    for (int i = 0; i < 16; i++) s += red[i];
    out[0] = s * (1.0f / BATCH);
  }
}

extern "C" void kernel_launch(void* const* d_in, const int* in_sizes, int n_in,
                              void* d_out, int out_size, void* d_ws, size_t ws_size,
                              hipStream_t stream) {
  const float* feat    = (const float*)d_in[0];
  const int*   label   = (const int*)d_in[1];
  const float* centers = (const float*)d_in[2];

  float* out        = (float*)d_out;
  float* out_logits = out;
  float* out_margin = out + (size_t)BATCH * NCLS;
  float* out_lik    = out + 2 * (size_t)BATCH * NCLS;

  char* ws = (char*)d_ws;
  unsigned short* fbf = (unsigned short*)ws;                                   // 4 MB
  unsigned short* cbf = (unsigned short*)(ws + (size_t)BATCH * FDIM * 2);      // 5 MB
  float* fsq     = (float*)(ws + (size_t)BATCH * FDIM * 2 + (size_t)NCLS * FDIM * 2);
  float* csq     = fsq + BATCH;
  float* lik_row = csq + NCLS;

  prep_kernel<<<(BATCH + NCLS) / 4, 256, 0, stream>>>(feat, centers, fbf, cbf, fsq, csq);
  gemm_kernel<<<(BATCH / BM) * ((NCLS + BN - 1) / BN), 512, 0, stream>>>(
      fbf, cbf, fsq, csq, label, out_logits, out_margin, lik_row);
  lik_reduce_kernel<<<1, 1024, 0, stream>>>(lik_row, out_lik);
}

// Round 17
// 216.837 us; speedup vs baseline: 1.0941x; 1.0813x over previous
//
#include <hip/hip_runtime.h>
#include <hip/hip_bf16.h>

// LGM loss: logits/margin_logits [8192,10000] f32 + scalar likelihood.
// R17: TWO-STREAM test. R16 killed the transaction-shape theory
// (full-line 512B stores, unconfounded: regressed). Last untested
// difference vs the 6.7 TB/s fill kernel: it writes ONE stream; our
// epilogue ping-pongs every 16B between out_logits and out_margin (327MB
// apart) -> two open page-streams per CU, half burst length per stream.
// Fix: two passes over live acc; pass 0 stores only one buffer, pass 1
// only the other; block parity (bid&1) alternates order so both streams
// are continuously fed chip-wide. Everything else = R14 (best, 197us):
// halo frags, parity-aligned windows, dbuf reg-staged LDS, XOR swizzle,
// nt-fastest XCD map, lik fold (margin pass).

#define ALPHA_ 0.1f
constexpr int BATCH = 8192;
constexpr int NCLS  = 10000;
constexpr int FDIM  = 256;

typedef __attribute__((ext_vector_type(8))) short bf16x8;
typedef __attribute__((ext_vector_type(4))) float f32x4;

__device__ __forceinline__ unsigned short f2bf(float f) {
  unsigned int u = __float_as_uint(f);
  u += 0x7FFF + ((u >> 16) & 1);   // round-to-nearest-even
  return (unsigned short)(u >> 16);
}

// One wave per row: convert f32 row -> bf16 into ws, and compute sum(x*x).
__global__ void prep_kernel(const float* __restrict__ feat,
                            const float* __restrict__ centers,
                            unsigned short* __restrict__ fbf,
                            unsigned short* __restrict__ cbf,
                            float* __restrict__ fsq,
                            float* __restrict__ csq) {
  int gw = (int)((blockIdx.x * blockDim.x + threadIdx.x) >> 6);
  int lane = threadIdx.x & 63;
  if (gw >= BATCH + NCLS) return;
  const float* src; unsigned short* dst; float* sq;
  if (gw < BATCH) {
    src = feat + (size_t)gw * FDIM; dst = fbf + (size_t)gw * FDIM; sq = fsq + gw;
  } else {
    int r = gw - BATCH;
    src = centers + (size_t)r * FDIM; dst = cbf + (size_t)r * FDIM; sq = csq + r;
  }
  float4 v = reinterpret_cast<const float4*>(src)[lane];   // 64 lanes x 16B = 256 f32
  ushort4 b;
  b.x = f2bf(v.x); b.y = f2bf(v.y); b.z = f2bf(v.z); b.w = f2bf(v.w);
  reinterpret_cast<ushort4*>(dst)[lane] = b;
  float s = v.x*v.x + v.y*v.y + v.z*v.z + v.w*v.w;
  #pragma unroll
  for (int off = 32; off >= 1; off >>= 1) s += __shfl_xor(s, off, 64);
  if (lane == 0) *sq = s;
}

// 128x128 tile (+16-col B halo), BK=64, 8 waves (2Mx4N), wave = 64x32 (+16 halo).
#define BM 128
#define BN 128
#define BK 64
#define BROWS 144   // 16-row halo + 128

__global__ __launch_bounds__(512, 4)
void gemm_kernel(const unsigned short* __restrict__ fbf,
                 const unsigned short* __restrict__ cbf,
                 const float* __restrict__ fsq,
                 const float* __restrict__ csq,
                 const int* __restrict__ label,
                 float* __restrict__ out_logits,
                 float* __restrict__ out_margin,
                 float* __restrict__ lik_row) {
  // Double-buffered, XOR-swizzled (slot = chunk ^ (row&7), 16B chunks).
  __shared__ unsigned short As[2][BM * BK];      // 16 KB each
  __shared__ unsigned short Bs[2][BROWS * BK];   // 18 KB each -> 68 KB total

  const int NTN = (NCLS + BN - 1) / BN;  // 79
  const int NWG = (BATCH / BM) * NTN;    // 5056 == 8 * 632

  // XCD-bijective split, nt-fastest within each XCD chunk.
  int bid = blockIdx.x;
  int wg = (bid & 7) * (NWG >> 3) + (bid >> 3);
  int mt = wg / NTN;
  int nt = wg - mt * NTN;

  const int tid  = threadIdx.x;
  const int lane = tid & 63;
  const int wid  = tid >> 6;            // 0..7
  const int wr   = (wid >> 2) * 64;     // 2 waves in M
  const int wc   = (wid & 3) * 32;      // 4 waves in N
  const int sr   = tid >> 3;            // staging row 0..63
  const int sc   = tid & 7;             // staging 16B chunk 0..7
  const int mloc  = wr + (lane & 15);

  const size_t a_base = (size_t)(mt * BM) * FDIM;
  const int c0 = nt * BN;

  f32x4 acc[4][3];   // 3 N-frags: j=0 is the 16-col halo at wc-16
  #pragma unroll
  for (int i = 0; i < 4; i++)
    #pragma unroll
    for (int j = 0; j < 3; j++) acc[i][j] = (f32x4){0.f, 0.f, 0.f, 0.f};

  bf16x8 va[2], vb[2], vbh;

  // Bs row r <-> class c0 - 16 + r, r in [0,144).
  #define LOADT(k0_) do {                                                      \
    _Pragma("unroll")                                                          \
    for (int j = 0; j < 2; ++j) {                                              \
      int r = j * 64 + sr;                                                     \
      va[j] = *reinterpret_cast<const bf16x8*>(fbf + a_base + (size_t)r * FDIM + (k0_) + sc * 8); \
      int cc = c0 + r; cc = (cc < NCLS) ? cc : (NCLS - 1);                     \
      vb[j] = *reinterpret_cast<const bf16x8*>(cbf + (size_t)cc * FDIM + (k0_) + sc * 8); \
    }                                                                          \
    if (tid < 128) {                                                           \
      int ch_ = c0 - 16 + (tid >> 3); ch_ = (ch_ >= 0) ? ch_ : 0;              \
      vbh = *reinterpret_cast<const bf16x8*>(cbf + (size_t)ch_ * FDIM + (k0_) + sc * 8); \
    }                                                                          \
  } while (0)

  #define STORET(b_) do {                                                      \
    _Pragma("unroll")                                                          \
    for (int j = 0; j < 2; ++j) {                                              \
      int r = j * 64 + sr;                                                     \
      int offa = r * BK + ((sc ^ (r & 7)) * 8);                                \
      *reinterpret_cast<bf16x8*>(&As[b_][offa]) = va[j];                       \
      int rb = r + 16;                                                         \
      int offb = rb * BK + ((sc ^ (rb & 7)) * 8);                              \
      *reinterpret_cast<bf16x8*>(&Bs[b_][offb]) = vb[j];                       \
    }                                                                          \
    if (tid < 128) {                                                           \
      int rh = tid >> 3;                                                       \
      int offh = rh * BK + ((sc ^ (rh & 7)) * 8);                              \
      *reinterpret_cast<bf16x8*>(&Bs[b_][offh]) = vbh;                         \
    }                                                                          \
  } while (0)

  LOADT(0);
  STORET(0);

  #pragma unroll
  for (int kc = 0; kc < FDIM / BK; ++kc) {
    const int cur = kc & 1;
    if (kc < FDIM / BK - 1) LOADT((kc + 1) * BK);
    __syncthreads();                          // buf[cur] writes visible
    #pragma unroll
    for (int kk = 0; kk < BK / 32; ++kk) {
      const int ch = kk * 4 + (lane >> 4);    // 16B chunk within row
      bf16x8 a[4], b[3];
      #pragma unroll
      for (int i = 0; i < 4; i++) {
        int row = wr + i * 16 + (lane & 15);
        a[i] = *reinterpret_cast<const bf16x8*>(&As[cur][row * BK + ((ch ^ (row & 7)) * 8)]);
      }
      #pragma unroll
      for (int j = 0; j < 3; j++) {
        int row = wc + j * 16 + (lane & 15);  // class c0 + wc + (j-1)*16 + (lane&15)
        b[j] = *reinterpret_cast<const bf16x8*>(&Bs[cur][row * BK + ((ch ^ (row & 7)) * 8)]);
      }
      // Swapped operands: per lane, reg r = 4 consecutive N columns at one M row.
      #pragma unroll
      for (int i = 0; i < 4; i++)
        #pragma unroll
        for (int j = 0; j < 3; j++)
          acc[i][j] = __builtin_amdgcn_mfma_f32_16x16x32_bf16(b[j], a[i], acc[i][j], 0, 0, 0);
    }
    if (kc < FDIM / BK - 1) STORET(cur ^ 1);  // fill other buffer
  }

  // Epilogue: stream-segregated, parity-aligned windows (R14 coverage).
  // pass 0 writes stream (bid&1), pass 1 writes the other stream.
  const int p   = lane & 1;
  const int par = bid & 1;
  #pragma unroll
  for (int pass = 0; pass < 2; ++pass) {
    const int stream_margin = par ^ pass;   // 0 -> logits, 1 -> margin
    #pragma unroll
    for (int i = 0; i < 4; i++) {
      int m = mt * BM + mloc + i * 16;
      float fs = fsq[m];
      int lb = label[m];
      size_t rowoff = (size_t)m * NCLS;
      #pragma unroll
      for (int j = 0; j < 3; j++) {
        if (p ? (j >= 2) : (j == 0)) continue;
        int n0 = c0 + wc + (j - 1) * 16 + ((lane >> 4) << 2);
        if (n0 < 0 || n0 >= NCLS) continue;  // n0%4==0, NCLS%4==0 -> all-or-nothing
        float4 cs = *reinterpret_cast<const float4*>(&csq[n0]);
        f32x4 v = acc[i][j];
        f32x4 lg;
        lg[0] = v[0] - 0.5f * (fs + cs.x);
        lg[1] = v[1] - 0.5f * (fs + cs.y);
        lg[2] = v[2] - 0.5f * (fs + cs.z);
        lg[3] = v[3] - 0.5f * (fs + cs.w);
        if (stream_margin == 0) {
          *reinterpret_cast<f32x4*>(&out_logits[rowoff + n0]) = lg;
        } else {
          f32x4 mg;
          mg[0] = (lb == n0    ) ? lg[0] * (1.0f + ALPHA_) : lg[0];
          mg[1] = (lb == n0 + 1) ? lg[1] * (1.0f + ALPHA_) : lg[1];
          mg[2] = (lb == n0 + 2) ? lg[2] * (1.0f + ALPHA_) : lg[2];
          mg[3] = (lb == n0 + 3) ? lg[3] * (1.0f + ALPHA_) : lg[3];
          *reinterpret_cast<f32x4*>(&out_margin[rowoff + n0]) = mg;
          if (lb >= n0 && lb < n0 + 4) {
            float lv = (lb == n0) ? lg[0] : (lb == n0 + 1) ? lg[1]
                     : (lb == n0 + 2) ? lg[2] : lg[3];
            lik_row[m] = -lv;   // parity windows partition cols -> one writer
          }
        }
      }
    }
  }
  #undef LOADT
  #undef STORET
}

// likelihood = (1/B) * sum_m lik_row[m]; 1024 threads, deterministic tree.
__global__ void lik_reduce_kernel(const float* __restrict__ lik_row,
                                  float* __restrict__ out) {
  int t = threadIdx.x;  // 1024
  float v = 0.f;
  #pragma unroll
  for (int i = 0; i < BATCH / 1024; i++) v += lik_row[t + i * 1024];
  #pragma unroll
  for (int off = 32; off >= 1; off >>= 1) v += __shfl_xor(v, off, 64);
  __shared__ float red[16];
  if ((t & 63) == 0) red[t >> 6] = v;
  __syncthreads();
  if (t == 0) {
    float s = 0.f;
    #pragma unroll
    for (int i = 0; i < 16; i++) s += red[i];
    out[0] = s * (1.0f / BATCH);
  }
}

extern "C" void kernel_launch(void* const* d_in, const int* in_sizes, int n_in,
                              void* d_out, int out_size, void* d_ws, size_t ws_size,
                              hipStream_t stream) {
  const float* feat    = (const float*)d_in[0];
  const int*   label   = (const int*)d_in[1];
  const float* centers = (const float*)d_in[2];

  float* out        = (float*)d_out;
  float* out_logits = out;
  float* out_margin = out + (size_t)BATCH * NCLS;
  float* out_lik    = out + 2 * (size_t)BATCH * NCLS;

  char* ws = (char*)d_ws;
  unsigned short* fbf = (unsigned short*)ws;                                   // 4 MB
  unsigned short* cbf = (unsigned short*)(ws + (size_t)BATCH * FDIM * 2);      // 5 MB
  float* fsq     = (float*)(ws + (size_t)BATCH * FDIM * 2 + (size_t)NCLS * FDIM * 2);
  float* csq     = fsq + BATCH;
  float* lik_row = csq + NCLS;

  prep_kernel<<<(BATCH + NCLS) / 4, 256, 0, stream>>>(feat, centers, fbf, cbf, fsq, csq);
  gemm_kernel<<<(BATCH / BM) * ((NCLS + BN - 1) / BN), 512, 0, stream>>>(
      fbf, cbf, fsq, csq, label, out_logits, out_margin, lik_row);
  lik_reduce_kernel<<<1, 1024, 0, stream>>>(lik_row, out_lik);
}

// Round 18
// 198.900 us; speedup vs baseline: 1.1928x; 1.0902x over previous
//
#include <hip/hip_runtime.h>
#include <hip/hip_bf16.h>

// LGM loss: logits/margin_logits [8192,10000] f32 + scalar likelihood.
// R18 = REVERT to R14 (best, 197us). R15/R16/R17 all regressed; every
// memory-side mechanism is now tested and falsified (see ledger). This
// kernel's ~3.9 TB/s effective rate on the 40KB-strided dual-output write
// pattern is the measured structural ceiling; final kernel.
// R14: parity-aligned stores (row stride 40000B == 64 mod 128 -> odd rows
// get a 16-col-shifted window so every run starts 0 mod 128), 16-col halo
// frag, reg-staged dbuf LDS, XOR swizzle, nt-fastest XCD map, lik fold.

#define ALPHA_ 0.1f
constexpr int BATCH = 8192;
constexpr int NCLS  = 10000;
constexpr int FDIM  = 256;

typedef __attribute__((ext_vector_type(8))) short bf16x8;
typedef __attribute__((ext_vector_type(4))) float f32x4;

__device__ __forceinline__ unsigned short f2bf(float f) {
  unsigned int u = __float_as_uint(f);
  u += 0x7FFF + ((u >> 16) & 1);   // round-to-nearest-even
  return (unsigned short)(u >> 16);
}

// One wave per row: convert f32 row -> bf16 into ws, and compute sum(x*x).
__global__ void prep_kernel(const float* __restrict__ feat,
                            const float* __restrict__ centers,
                            unsigned short* __restrict__ fbf,
                            unsigned short* __restrict__ cbf,
                            float* __restrict__ fsq,
                            float* __restrict__ csq) {
  int gw = (int)((blockIdx.x * blockDim.x + threadIdx.x) >> 6);
  int lane = threadIdx.x & 63;
  if (gw >= BATCH + NCLS) return;
  const float* src; unsigned short* dst; float* sq;
  if (gw < BATCH) {
    src = feat + (size_t)gw * FDIM; dst = fbf + (size_t)gw * FDIM; sq = fsq + gw;
  } else {
    int r = gw - BATCH;
    src = centers + (size_t)r * FDIM; dst = cbf + (size_t)r * FDIM; sq = csq + r;
  }
  float4 v = reinterpret_cast<const float4*>(src)[lane];   // 64 lanes x 16B = 256 f32
  ushort4 b;
  b.x = f2bf(v.x); b.y = f2bf(v.y); b.z = f2bf(v.z); b.w = f2bf(v.w);
  reinterpret_cast<ushort4*>(dst)[lane] = b;
  float s = v.x*v.x + v.y*v.y + v.z*v.z + v.w*v.w;
  #pragma unroll
  for (int off = 32; off >= 1; off >>= 1) s += __shfl_xor(s, off, 64);
  if (lane == 0) *sq = s;
}

// 128x128 tile (+16-col B halo), BK=64, 8 waves (2Mx4N), wave = 64x32 (+16 halo).
#define BM 128
#define BN 128
#define BK 64
#define BROWS 144   // 16-row halo + 128

__global__ __launch_bounds__(512, 4)
void gemm_kernel(const unsigned short* __restrict__ fbf,
                 const unsigned short* __restrict__ cbf,
                 const float* __restrict__ fsq,
                 const float* __restrict__ csq,
                 const int* __restrict__ label,
                 float* __restrict__ out_logits,
                 float* __restrict__ out_margin,
                 float* __restrict__ lik_row) {
  // Double-buffered, XOR-swizzled (slot = chunk ^ (row&7), 16B chunks).
  __shared__ unsigned short As[2][BM * BK];      // 16 KB each
  __shared__ unsigned short Bs[2][BROWS * BK];   // 18 KB each -> 68 KB total

  const int NTN = (NCLS + BN - 1) / BN;  // 79
  const int NWG = (BATCH / BM) * NTN;    // 5056 == 8 * 632

  // XCD-bijective split, nt-fastest within each XCD chunk.
  int bid = blockIdx.x;
  int wg = (bid & 7) * (NWG >> 3) + (bid >> 3);
  int mt = wg / NTN;
  int nt = wg - mt * NTN;

  const int tid  = threadIdx.x;
  const int lane = tid & 63;
  const int wid  = tid >> 6;            // 0..7
  const int wr   = (wid >> 2) * 64;     // 2 waves in M
  const int wc   = (wid & 3) * 32;      // 4 waves in N
  const int sr   = tid >> 3;            // staging row 0..63
  const int sc   = tid & 7;             // staging 16B chunk 0..7
  const int mloc  = wr + (lane & 15);

  const size_t a_base = (size_t)(mt * BM) * FDIM;
  const int c0 = nt * BN;

  f32x4 acc[4][3];   // 3 N-frags: j=0 is the 16-col halo at wc-16
  #pragma unroll
  for (int i = 0; i < 4; i++)
    #pragma unroll
    for (int j = 0; j < 3; j++) acc[i][j] = (f32x4){0.f, 0.f, 0.f, 0.f};

  bf16x8 va[2], vb[2], vbh;

  // Bs row r <-> class c0 - 16 + r, r in [0,144).
  #define LOADT(k0_) do {                                                      \
    _Pragma("unroll")                                                          \
    for (int j = 0; j < 2; ++j) {                                              \
      int r = j * 64 + sr;                                                     \
      va[j] = *reinterpret_cast<const bf16x8*>(fbf + a_base + (size_t)r * FDIM + (k0_) + sc * 8); \
      int cc = c0 + r; cc = (cc < NCLS) ? cc : (NCLS - 1);                     \
      vb[j] = *reinterpret_cast<const bf16x8*>(cbf + (size_t)cc * FDIM + (k0_) + sc * 8); \
    }                                                                          \
    if (tid < 128) {                                                           \
      int ch_ = c0 - 16 + (tid >> 3); ch_ = (ch_ >= 0) ? ch_ : 0;              \
      vbh = *reinterpret_cast<const bf16x8*>(cbf + (size_t)ch_ * FDIM + (k0_) + sc * 8); \
    }                                                                          \
  } while (0)

  #define STORET(b_) do {                                                      \
    _Pragma("unroll")                                                          \
    for (int j = 0; j < 2; ++j) {                                              \
      int r = j * 64 + sr;                                                     \
      int offa = r * BK + ((sc ^ (r & 7)) * 8);                                \
      *reinterpret_cast<bf16x8*>(&As[b_][offa]) = va[j];                       \
      int rb = r + 16;                                                         \
      int offb = rb * BK + ((sc ^ (rb & 7)) * 8);                              \
      *reinterpret_cast<bf16x8*>(&Bs[b_][offb]) = vb[j];                       \
    }                                                                          \
    if (tid < 128) {                                                           \
      int rh = tid >> 3;                                                       \
      int offh = rh * BK + ((sc ^ (rh & 7)) * 8);                              \
      *reinterpret_cast<bf16x8*>(&Bs[b_][offh]) = vbh;                         \
    }                                                                          \
  } while (0)

  LOADT(0);
  STORET(0);

  #pragma unroll
  for (int kc = 0; kc < FDIM / BK; ++kc) {
    const int cur = kc & 1;
    if (kc < FDIM / BK - 1) LOADT((kc + 1) * BK);
    __syncthreads();                          // buf[cur] writes visible
    #pragma unroll
    for (int kk = 0; kk < BK / 32; ++kk) {
      const int ch = kk * 4 + (lane >> 4);    // 16B chunk within row
      bf16x8 a[4], b[3];
      #pragma unroll
      for (int i = 0; i < 4; i++) {
        int row = wr + i * 16 + (lane & 15);
        a[i] = *reinterpret_cast<const bf16x8*>(&As[cur][row * BK + ((ch ^ (row & 7)) * 8)]);
      }
      #pragma unroll
      for (int j = 0; j < 3; j++) {
        int row = wc + j * 16 + (lane & 15);  // class c0 + wc + (j-1)*16 + (lane&15)
        b[j] = *reinterpret_cast<const bf16x8*>(&Bs[cur][row * BK + ((ch ^ (row & 7)) * 8)]);
      }
      // Swapped operands: per lane, reg r = 4 consecutive N columns at one M row.
      #pragma unroll
      for (int i = 0; i < 4; i++)
        #pragma unroll
        for (int j = 0; j < 3; j++)
          acc[i][j] = __builtin_amdgcn_mfma_f32_16x16x32_bf16(b[j], a[i], acc[i][j], 0, 0, 0);
    }
    if (kc < FDIM / BK - 1) STORET(cur ^ 1);  // fill other buffer
  }

  // Epilogue with parity-aligned windows.
  // Lane's rows have parity p = lane&1 (mt*128, wr, i*16 all even).
  // Store frag j at n0 = c0 + wc + (j-1)*16 + (lane>>4)*4:
  //   even rows (p=0): j=1,2  -> cols [c0+wc, +32), 128B-aligned rows
  //   odd  rows (p=1): j=0,1  -> cols [c0+wc-16, +16), start also 0 mod 128
  const int p = lane & 1;
  #pragma unroll
  for (int i = 0; i < 4; i++) {
    int m = mt * BM + mloc + i * 16;
    float fs = fsq[m];
    int lb = label[m];
    size_t rowoff = (size_t)m * NCLS;
    #pragma unroll
    for (int j = 0; j < 3; j++) {
      if (p ? (j >= 2) : (j == 0)) continue;
      int n0 = c0 + wc + (j - 1) * 16 + ((lane >> 4) << 2);
      if (n0 < 0 || n0 >= NCLS) continue;  // n0%4==0, NCLS%4==0 -> all-or-nothing
      float4 cs = *reinterpret_cast<const float4*>(&csq[n0]);
      f32x4 v = acc[i][j];
      f32x4 lg;
      lg[0] = v[0] - 0.5f * (fs + cs.x);
      lg[1] = v[1] - 0.5f * (fs + cs.y);
      lg[2] = v[2] - 0.5f * (fs + cs.z);
      lg[3] = v[3] - 0.5f * (fs + cs.w);
      *reinterpret_cast<f32x4*>(&out_logits[rowoff + n0]) = lg;
      f32x4 mg;
      mg[0] = (lb == n0    ) ? lg[0] * (1.0f + ALPHA_) : lg[0];
      mg[1] = (lb == n0 + 1) ? lg[1] * (1.0f + ALPHA_) : lg[1];
      mg[2] = (lb == n0 + 2) ? lg[2] * (1.0f + ALPHA_) : lg[2];
      mg[3] = (lb == n0 + 3) ? lg[3] * (1.0f + ALPHA_) : lg[3];
      *reinterpret_cast<f32x4*>(&out_margin[rowoff + n0]) = mg;
      if (lb >= n0 && lb < n0 + 4) {
        float lv = (lb == n0) ? lg[0] : (lb == n0 + 1) ? lg[1]
                 : (lb == n0 + 2) ? lg[2] : lg[3];
        lik_row[m] = -lv;   // exactly-once partition per parity -> one writer
      }
    }
  }
  #undef LOADT
  #undef STORET
}

// likelihood = (1/B) * sum_m lik_row[m]; 1024 threads, deterministic tree.
__global__ void lik_reduce_kernel(const float* __restrict__ lik_row,
                                  float* __restrict__ out) {
  int t = threadIdx.x;  // 1024
  float v = 0.f;
  #pragma unroll
  for (int i = 0; i < BATCH / 1024; i++) v += lik_row[t + i * 1024];
  #pragma unroll
  for (int off = 32; off >= 1; off >>= 1) v += __shfl_xor(v, off, 64);
  __shared__ float red[16];
  if ((t & 63) == 0) red[t >> 6] = v;
  __syncthreads();
  if (t == 0) {
    float s = 0.f;
    #pragma unroll
    for (int i = 0; i < 16; i++) s += red[i];
    out[0] = s * (1.0f / BATCH);
  }
}

extern "C" void kernel_launch(void* const* d_in, const int* in_sizes, int n_in,
                              void* d_out, int out_size, void* d_ws, size_t ws_size,
                              hipStream_t stream) {
  const float* feat    = (const float*)d_in[0];
  const int*   label   = (const int*)d_in[1];
  const float* centers = (const float*)d_in[2];

  float* out        = (float*)d_out;
  float* out_logits = out;
  float* out_margin = out + (size_t)BATCH * NCLS;
  float* out_lik    = out + 2 * (size_t)BATCH * NCLS;

  char* ws = (char*)d_ws;
  unsigned short* fbf = (unsigned short*)ws;                                   // 4 MB
  unsigned short* cbf = (unsigned short*)(ws + (size_t)BATCH * FDIM * 2);      // 5 MB
  float* fsq     = (float*)(ws + (size_t)BATCH * FDIM * 2 + (size_t)NCLS * FDIM * 2);
  float* csq     = fsq + BATCH;
  float* lik_row = csq + NCLS;

  prep_kernel<<<(BATCH + NCLS) / 4, 256, 0, stream>>>(feat, centers, fbf, cbf, fsq, csq);
  gemm_kernel<<<(BATCH / BM) * ((NCLS + BN - 1) / BN), 512, 0, stream>>>(
      fbf, cbf, fsq, csq, label, out_logits, out_margin, lik_row);
  lik_reduce_kernel<<<1, 1024, 0, stream>>>(lik_row, out_lik);
}